// Round 9
// baseline (324.947 us; speedup 1.0000x reference)
//
#include <hip/hip_runtime.h>
#include <math.h>

// Problem constants (from reference)
constexpr int    N       = 8388608;   // B
constexpr int    THREADS = 256;
constexpr int    BLOCKS  = 2048;      // keeps partials workspace at 2048*9*8 = 144 KiB
constexpr int    VEC     = 4;
constexpr int    ITERS   = N / (BLOCKS * THREADS * VEC);  // = 4, exact
constexpr int    STRIDE  = BLOCKS * THREADS;
constexpr int    NSUMS   = 9;
// sum layout: 0:Σs 1:Σm 2:Σl 3:Σs² 4:Σm² 5:Σl² 6:Σsm 7:Σsl 8:Σml
// out layout: [0,N) total | [N] ortho | [N+1,2N+1) r_short | [2N+1,3N+1) r_mid | [3N+1,4N+1) r_long

static_assert(ITERS == 4, "grid math");

// 4-byte-aligned 16-byte access: gfx950 global load/store need only dword
// alignment. Verified round 8: no write amplification (WRITE_SIZE == logical),
// no shuffles/patches needed. Plain (non-NT) stores only — NT caused 2x write
// amplification (round 2).
struct __attribute__((packed, aligned(4))) f4u { float x, y, z, w; };

__device__ inline void store4_u(float* p, float a, float b, float c, float d) {
    f4u v{a, b, c, d};
    *reinterpret_cast<f4u*>(p) = v;
}
__device__ inline f4u load4_u(const float* p) {
    return *reinterpret_cast<const f4u*>(p);
}

__device__ inline double wave_reduce(double x) {
#pragma unroll
    for (int off = 32; off > 0; off >>= 1)
        x += __shfl_down(x, off, 64);
    return x;
}

// ---------------------------------------------------------------------------
// Temporal phase split: each kernel is a 3-4-stream pure streaming op.
// Hypothesis: the fused kernel's 10 concurrent streams x 2048 resident block
// positions thrash DRAM open rows, capping effective BW at ~3.3 TB/s; few-
// stream phases should each run near the ~6 TB/s copy ceiling. Phase D reads
// rs/rm/rl while still L3-resident (just written) and computes total_reward
// plus all 9 correlation sums (needs all three co-located).
// Values are bit-identical to the fused version: same f32 expressions,
// f32 store/load round-trip is lossless.
// ---------------------------------------------------------------------------

// Phase A: r_short = cq - pq              (2 read streams + 1 write stream)
__global__ __launch_bounds__(THREADS) void phase_rs(
    const float* __restrict__ cq, const float* __restrict__ pq,
    float* __restrict__ out)
{
    const float4* cq4 = (const float4*)cq;
    const float4* pq4 = (const float4*)pq;
    const int tid = blockIdx.x * THREADS + threadIdx.x;
#pragma unroll
    for (int it = 0; it < ITERS; ++it) {
        const int idx4 = tid + it * STRIDE;
        float4 q = cq4[idx4];
        float4 p = pq4[idx4];
        store4_u(out + N + 1 + 4 * idx4,
                 q.x - p.x, q.y - p.y, q.z - p.z, q.w - p.w);
    }
}

// Phase B: r_long = fq + 0.5*(1 - sc/ms)  (2 read streams + 1 write stream)
__global__ __launch_bounds__(THREADS) void phase_rl(
    const float* __restrict__ sc, const float* __restrict__ fq,
    const int* __restrict__ ms_p, float* __restrict__ out)
{
    const float ms = (float)ms_p[0];
    const float inv_ms = 1.0f / ms;
    const float4* sc4 = (const float4*)sc;
    const float4* fq4 = (const float4*)fq;
    const int tid = blockIdx.x * THREADS + threadIdx.x;
#pragma unroll
    for (int it = 0; it < ITERS; ++it) {
        const int idx4 = tid + it * STRIDE;
        float4 s = sc4[idx4];
        float4 f = fq4[idx4];
        store4_u(out + 3 * N + 1 + 4 * idx4,
                 f.x + 0.5f * (1.0f - s.x * inv_ms),
                 f.y + 0.5f * (1.0f - s.y * inv_ms),
                 f.z + 0.5f * (1.0f - s.z * inv_ms),
                 f.w + 0.5f * (1.0f - s.w * inv_ms));
    }
}

// Phase C: r_mid from un, ac, sc          (3 read streams + 1 write stream;
//                                          sc likely L3-hot from phase B)
__device__ inline float rm_elem(float u, int a, float sc, float ms, float inv_ms) {
    float stop_r = (u < 0.3f) ? 0.5f : ((u > 0.7f) ? -0.5f : 0.0f);
    float cont = (u > 0.5f) ? (0.5f * u) : (-0.5f * (1.0f - u));
    cont -= (sc > 0.8f * ms) ? 0.3f : 0.0f;   // 0.8f*20.0f == 16.0f exactly
    float t = sc * inv_ms;
    return ((a == 0) ? stop_r : cont) - 0.1f * t;
}

__global__ __launch_bounds__(THREADS) void phase_rm(
    const float* __restrict__ un, const int* __restrict__ ac,
    const float* __restrict__ sc, const int* __restrict__ ms_p,
    float* __restrict__ out)
{
    const float ms = (float)ms_p[0];
    const float inv_ms = 1.0f / ms;
    const float4* un4 = (const float4*)un;
    const int4*   ac4 = (const int4*)ac;
    const float4* sc4 = (const float4*)sc;
    const int tid = blockIdx.x * THREADS + threadIdx.x;
#pragma unroll
    for (int it = 0; it < ITERS; ++it) {
        const int idx4 = tid + it * STRIDE;
        float4 u = un4[idx4];
        int4   a = ac4[idx4];
        float4 s = sc4[idx4];
        store4_u(out + 2 * N + 1 + 4 * idx4,
                 rm_elem(u.x, a.x, s.x, ms, inv_ms),
                 rm_elem(u.y, a.y, s.y, ms, inv_ms),
                 rm_elem(u.z, a.z, s.z, ms, inv_ms),
                 rm_elem(u.w, a.w, s.w, ms, inv_ms));
    }
}

// Phase D: total = a*rs + b*rm + g*rl; all 9 partial sums.
//          (3 read streams, all L3-hot, + 1 write stream + partials)
__global__ __launch_bounds__(THREADS) void phase_tt(
    const float* __restrict__ alpha_p, const float* __restrict__ beta_p,
    const float* __restrict__ gamma_p,
    float* __restrict__ out, double* __restrict__ partials)
{
    const float alpha = alpha_p[0], beta = beta_p[0], gamma = gamma_p[0];

    double acc[NSUMS];
#pragma unroll
    for (int s = 0; s < NSUMS; ++s) acc[s] = 0.0;

    const int tid  = blockIdx.x * THREADS + threadIdx.x;
    const int lane = threadIdx.x & 63;

#pragma unroll
    for (int it = 0; it < ITERS; ++it) {
        const int idx4 = tid + it * STRIDE;
        const int b = 4 * idx4;
        f4u rs = load4_u(out +     N + 1 + b);
        f4u rm = load4_u(out + 2 * N + 1 + b);
        f4u rl = load4_u(out + 3 * N + 1 + b);

        float rsv[4] = {rs.x, rs.y, rs.z, rs.w};
        float rmv[4] = {rm.x, rm.y, rm.z, rm.w};
        float rlv[4] = {rl.x, rl.y, rl.z, rl.w};
        float tt[4];
#pragma unroll
        for (int k = 0; k < 4; ++k) {
            tt[k] = alpha * rsv[k] + beta * rmv[k] + gamma * rlv[k];
            double ds = (double)rsv[k], dm = (double)rmv[k], dl = (double)rlv[k];
            acc[0] += ds;      acc[1] += dm;      acc[2] += dl;
            acc[3] += ds * ds; acc[4] += dm * dm; acc[5] += dl * dl;
            acc[6] += ds * dm; acc[7] += ds * dl; acc[8] += dm * dl;
        }
        *(float4*)(out + b) = make_float4(tt[0], tt[1], tt[2], tt[3]);
    }

    // block reduction of 9 sums
    __shared__ double red[NSUMS][THREADS / 64];
    const int wave = threadIdx.x >> 6;
#pragma unroll
    for (int s = 0; s < NSUMS; ++s) {
        double w = wave_reduce(acc[s]);
        if (lane == 0) red[s][wave] = w;
    }
    __syncthreads();
    if (threadIdx.x == 0) {
#pragma unroll
        for (int s = 0; s < NSUMS; ++s) {
            double t = 0.0;
#pragma unroll
            for (int w = 0; w < THREADS / 64; ++w) t += red[s][w];
            partials[blockIdx.x * NSUMS + s] = t;
        }
    }
}

__global__ __launch_bounds__(256) void reward_finish(const double* __restrict__ partials,
                                                     float* __restrict__ out)
{
    double loc[NSUMS];
#pragma unroll
    for (int s = 0; s < NSUMS; ++s) loc[s] = 0.0;
    for (int i = threadIdx.x; i < BLOCKS; i += 256) {
#pragma unroll
        for (int s = 0; s < NSUMS; ++s) loc[s] += partials[i * NSUMS + s];
    }
    __shared__ double red[NSUMS][4];
    const int lane = threadIdx.x & 63;
    const int wave = threadIdx.x >> 6;
#pragma unroll
    for (int s = 0; s < NSUMS; ++s) {
        double w = wave_reduce(loc[s]);
        if (lane == 0) red[s][wave] = w;
    }
    __syncthreads();
    if (threadIdx.x == 0) {
        double S[NSUMS];
#pragma unroll
        for (int s = 0; s < NSUMS; ++s)
            S[s] = red[s][0] + red[s][1] + red[s][2] + red[s][3];

        const double n = (double)N;
        double mx = S[0] / n, mm = S[1] / n, ml = S[2] / n;
        double cov_sm = S[6] / n - mx * mm;
        double cov_sl = S[7] / n - mx * ml;
        double cov_ml = S[8] / n - mm * ml;
        double sdS = sqrt((S[3] - n * mx * mx) / (n - 1.0)) + 1e-8;
        double sdM = sqrt((S[4] - n * mm * mm) / (n - 1.0)) + 1e-8;
        double sdL = sqrt((S[5] - n * ml * ml) / (n - 1.0)) + 1e-8;
        double c1 = cov_sm / (sdS * sdM);
        double c2 = cov_sl / (sdS * sdL);
        double c3 = cov_ml / (sdM * sdL);
        out[N] = (float)(c1 * c1 + c2 * c2 + c3 * c3);   // ORTHO_W = 1
    }
}

extern "C" void kernel_launch(void* const* d_in, const int* in_sizes, int n_in,
                              void* d_out, int out_size, void* d_ws, size_t ws_size,
                              hipStream_t stream)
{
    const float* cq   = (const float*)d_in[0];
    const float* pq   = (const float*)d_in[1];
    const float* un   = (const float*)d_in[2];
    const int*   ac   = (const int*)d_in[3];
    const float* sc   = (const float*)d_in[4];
    const float* fq   = (const float*)d_in[5];
    const float* alp  = (const float*)d_in[6];
    const float* bet  = (const float*)d_in[7];
    const float* gam  = (const float*)d_in[8];
    const int*   msp  = (const int*)d_in[9];
    float*  out      = (float*)d_out;
    double* partials = (double*)d_ws;   // 2048 * 9 * 8 B = 144 KiB

    // Sequential phases (stream-ordered => writes of each visible to next;
    // temporal separation keeps concurrent DRAM stream count at 3-4).
    phase_rs<<<BLOCKS, THREADS, 0, stream>>>(cq, pq, out);
    phase_rl<<<BLOCKS, THREADS, 0, stream>>>(sc, fq, msp, out);
    phase_rm<<<BLOCKS, THREADS, 0, stream>>>(un, ac, sc, msp, out);
    phase_tt<<<BLOCKS, THREADS, 0, stream>>>(alp, bet, gam, out, partials);
    reward_finish<<<1, 256, 0, stream>>>(partials, out);
}

// Round 10
// 311.596 us; speedup vs baseline: 1.0428x; 1.0428x over previous
//
#include <hip/hip_runtime.h>
#include <math.h>

// Problem constants (from reference)
constexpr int    N       = 8388608;   // B
constexpr int    THREADS = 256;
constexpr int    BLOCKS  = 2048;      // keeps partials workspace at 2048*9*8 = 144 KiB
constexpr int    CHUNK   = 8;         // elements per thread per iteration (2 x float4)
constexpr int    ITERS   = N / (BLOCKS * THREADS * CHUNK);  // = 2, exact
constexpr int    STRIDE  = BLOCKS * THREADS;                // thread-tiles per sweep
constexpr int    NSUMS   = 9;
// sum layout: 0:Σs 1:Σm 2:Σl 3:Σs² 4:Σm² 5:Σl² 6:Σsm 7:Σsl 8:Σml
// out layout: [0,N) total | [N] ortho | [N+1..) r_short | [2N+1..) r_mid | [3N+1..) r_long

static_assert(ITERS == 2, "grid math");

// 4-byte-aligned 16-byte store: gfx950 global stores need only dword
// alignment (verified round 8: WRITE_SIZE == logical, no amplification).
// Plain (non-NT) stores only — NT caused 2x write amplification (round 2).
struct __attribute__((packed, aligned(4))) f4u { float x, y, z, w; };

__device__ inline void store4_u(float* p, float a, float b, float c, float d) {
    f4u v{a, b, c, d};
    *reinterpret_cast<f4u*>(p) = v;
}

__device__ inline double wave_reduce(double x) {
#pragma unroll
    for (int off = 32; off > 0; off >>= 1)
        x += __shfl_down(x, off, 64);
    return x;
}

__device__ inline void elem_compute(float cq, float pq, float u, int a, float sc, float fq,
                                    float ms, float inv_ms,
                                    float alpha, float beta, float gamma,
                                    float& rs, float& rm, float& rl, float& tot)
{
    rs = cq - pq;
    float stop_r = (u < 0.3f) ? 0.5f : ((u > 0.7f) ? -0.5f : 0.0f);
    float cont = (u > 0.5f) ? (0.5f * u) : (-0.5f * (1.0f - u));
    cont -= (sc > 0.8f * ms) ? 0.3f : 0.0f;   // 0.8f*20.0f == 16.0f exactly, matches ref
    float t = sc * inv_ms;
    rm = ((a == 0) ? stop_r : cont) - 0.1f * t;
    rl = fq + 0.5f * (1.0f - t);
    tot = alpha * rs + beta * rm + gamma * rl;
}

// Contiguous CHUNK=8 layout: thread-tile idx8 covers elements [8*idx8, 8*idx8+8).
// Per wave per array per iteration, the two adjacent 16B accesses per thread
// tile a single contiguous 2 KB span -> batchable DRAM bursts per stream
// (vs round-8's 1KB islands 8MB apart across the k-loop). This is the last
// mechanism-backed lever against the mixed-stream turnaround penalty
// (pure-W fill: 6.7 TB/s; 10-stream fused: 3.3 TB/s).
__global__ __launch_bounds__(THREADS) void reward_main(
    const float* __restrict__ cq, const float* __restrict__ pq,
    const float* __restrict__ un, const int*  __restrict__ ac,
    const float* __restrict__ sc, const float* __restrict__ fq,
    const float* __restrict__ alpha_p, const float* __restrict__ beta_p,
    const float* __restrict__ gamma_p, const int* __restrict__ ms_p,
    float* __restrict__ out, double* __restrict__ partials)
{
    const float alpha = alpha_p[0], beta = beta_p[0], gamma = gamma_p[0];
    const float ms = (float)ms_p[0];
    const float inv_ms = 1.0f / ms;

    const float4* cq4 = (const float4*)cq;
    const float4* pq4 = (const float4*)pq;
    const float4* un4 = (const float4*)un;
    const int4*   ac4 = (const int4*)ac;
    const float4* sc4 = (const float4*)sc;
    const float4* fq4 = (const float4*)fq;

    double acc[NSUMS];
#pragma unroll
    for (int s = 0; s < NSUMS; ++s) acc[s] = 0.0;

    const int tid  = blockIdx.x * THREADS + threadIdx.x;   // 0 .. 524287
    const int lane = threadIdx.x & 63;

#pragma unroll
    for (int it = 0; it < ITERS; ++it) {
        const int idx8  = tid + it * STRIDE;    // thread-tile id, 0 .. N/8-1
        const int base4 = 2 * idx8;             // float4 index of first quad

        float4 qa = cq4[base4], qb = cq4[base4 + 1];
        float4 pa = pq4[base4], pb = pq4[base4 + 1];
        float4 ua = un4[base4], ub = un4[base4 + 1];
        int4   aa = ac4[base4], ab = ac4[base4 + 1];
        float4 sa = sc4[base4], sb = sc4[base4 + 1];
        float4 fa = fq4[base4], fb = fq4[base4 + 1];

        float qc[8] = {qa.x, qa.y, qa.z, qa.w, qb.x, qb.y, qb.z, qb.w};
        float pc[8] = {pa.x, pa.y, pa.z, pa.w, pb.x, pb.y, pb.z, pb.w};
        float uc[8] = {ua.x, ua.y, ua.z, ua.w, ub.x, ub.y, ub.z, ub.w};
        int   av[8] = {aa.x, aa.y, aa.z, aa.w, ab.x, ab.y, ab.z, ab.w};
        float sv[8] = {sa.x, sa.y, sa.z, sa.w, sb.x, sb.y, sb.z, sb.w};
        float fv[8] = {fa.x, fa.y, fa.z, fa.w, fb.x, fb.y, fb.z, fb.w};

        float rs[8], rm[8], rl[8], tt[8];
#pragma unroll
        for (int k = 0; k < 8; ++k) {
            elem_compute(qc[k], pc[k], uc[k], av[k], sv[k], fv[k],
                         ms, inv_ms, alpha, beta, gamma,
                         rs[k], rm[k], rl[k], tt[k]);
            double ds = (double)rs[k], dm = (double)rm[k], dl = (double)rl[k];
            acc[0] += ds;      acc[1] += dm;      acc[2] += dl;
            acc[3] += ds * ds; acc[4] += dm * dm; acc[5] += dl * dl;
            acc[6] += ds * dm; acc[7] += ds * dl; acc[8] += dm * dl;
        }

        const int b = 8 * idx8;   // element base for this thread

        // total_reward: aligned, two adjacent quads
        *(float4*)(out + b)     = make_float4(tt[0], tt[1], tt[2], tt[3]);
        *(float4*)(out + b + 4) = make_float4(tt[4], tt[5], tt[6], tt[7]);

        // +1 regions: direct 4B-aligned 16B stores, two adjacent quads each
        store4_u(out +     N + 1 + b,     rs[0], rs[1], rs[2], rs[3]);
        store4_u(out +     N + 1 + b + 4, rs[4], rs[5], rs[6], rs[7]);
        store4_u(out + 2 * N + 1 + b,     rm[0], rm[1], rm[2], rm[3]);
        store4_u(out + 2 * N + 1 + b + 4, rm[4], rm[5], rm[6], rm[7]);
        store4_u(out + 3 * N + 1 + b,     rl[0], rl[1], rl[2], rl[3]);
        store4_u(out + 3 * N + 1 + b + 4, rl[4], rl[5], rl[6], rl[7]);
    }

    // block reduction of 9 sums
    __shared__ double red[NSUMS][THREADS / 64];
    const int wave = threadIdx.x >> 6;
#pragma unroll
    for (int s = 0; s < NSUMS; ++s) {
        double w = wave_reduce(acc[s]);
        if (lane == 0) red[s][wave] = w;
    }
    __syncthreads();
    if (threadIdx.x == 0) {
#pragma unroll
        for (int s = 0; s < NSUMS; ++s) {
            double t = 0.0;
#pragma unroll
            for (int w = 0; w < THREADS / 64; ++w) t += red[s][w];
            partials[blockIdx.x * NSUMS + s] = t;
        }
    }
}

__global__ __launch_bounds__(256) void reward_finish(const double* __restrict__ partials,
                                                     float* __restrict__ out)
{
    double loc[NSUMS];
#pragma unroll
    for (int s = 0; s < NSUMS; ++s) loc[s] = 0.0;
    for (int i = threadIdx.x; i < BLOCKS; i += 256) {
#pragma unroll
        for (int s = 0; s < NSUMS; ++s) loc[s] += partials[i * NSUMS + s];
    }
    __shared__ double red[NSUMS][4];
    const int lane = threadIdx.x & 63;
    const int wave = threadIdx.x >> 6;
#pragma unroll
    for (int s = 0; s < NSUMS; ++s) {
        double w = wave_reduce(loc[s]);
        if (lane == 0) red[s][wave] = w;
    }
    __syncthreads();
    if (threadIdx.x == 0) {
        double S[NSUMS];
#pragma unroll
        for (int s = 0; s < NSUMS; ++s)
            S[s] = red[s][0] + red[s][1] + red[s][2] + red[s][3];

        const double n = (double)N;
        double mx = S[0] / n, mm = S[1] / n, ml = S[2] / n;
        double cov_sm = S[6] / n - mx * mm;
        double cov_sl = S[7] / n - mx * ml;
        double cov_ml = S[8] / n - mm * ml;
        double sdS = sqrt((S[3] - n * mx * mx) / (n - 1.0)) + 1e-8;
        double sdM = sqrt((S[4] - n * mm * mm) / (n - 1.0)) + 1e-8;
        double sdL = sqrt((S[5] - n * ml * ml) / (n - 1.0)) + 1e-8;
        double c1 = cov_sm / (sdS * sdM);
        double c2 = cov_sl / (sdS * sdL);
        double c3 = cov_ml / (sdM * sdL);
        out[N] = (float)(c1 * c1 + c2 * c2 + c3 * c3);   // ORTHO_W = 1
    }
}

extern "C" void kernel_launch(void* const* d_in, const int* in_sizes, int n_in,
                              void* d_out, int out_size, void* d_ws, size_t ws_size,
                              hipStream_t stream)
{
    const float* cq   = (const float*)d_in[0];
    const float* pq   = (const float*)d_in[1];
    const float* un   = (const float*)d_in[2];
    const int*   ac   = (const int*)d_in[3];
    const float* sc   = (const float*)d_in[4];
    const float* fq   = (const float*)d_in[5];
    const float* alp  = (const float*)d_in[6];
    const float* bet  = (const float*)d_in[7];
    const float* gam  = (const float*)d_in[8];
    const int*   msp  = (const int*)d_in[9];
    float*  out      = (float*)d_out;
    double* partials = (double*)d_ws;   // 2048 * 9 * 8 B = 144 KiB

    reward_main<<<BLOCKS, THREADS, 0, stream>>>(cq, pq, un, ac, sc, fq,
                                                alp, bet, gam, msp, out, partials);
    reward_finish<<<1, 256, 0, stream>>>(partials, out);
}